// Round 6
// baseline (277.760 us; speedup 1.0000x reference)
//
#include <hip/hip_runtime.h>
#include <cstdint>

// ---------------------------------------------------------------------------
// minerva_transform: logits = (l2(Xe) @ l2(De)^T)^3 @ rh ; preds = sigmoid
// R9 vs R8: k_minerva inner loop switched 16x16x32 -> 32x32x16 MFMA.
//   - per K-step: 16 MFMA x 8.07cyc (=129) vs 32 x 4.85 (=155); instruction
//     count halves, pipe ceiling 2495 vs 2176 TF (m119). Same ds_read bytes,
//     same 64 AGPR acc, same occupancy (VGPR 64+64=128 step).
//   - C/D layout (m74/m101, HW-verified): col=lane&31,
//     row=(reg&3)+8*(reg>>2)+4*(lane>>5); epilogue re-derived, atomics halve.
// k_prep / k_embed / k_weights / k_finalize unchanged from R8.
// ---------------------------------------------------------------------------

typedef __attribute__((ext_vector_type(4)))  float  f32x4;
typedef __attribute__((ext_vector_type(16))) float  f32x16;
typedef __attribute__((ext_vector_type(8))) __bf16 bf16x8;
typedef __attribute__((ext_vector_type(4))) __bf16 bf16x4;

constexpr int B = 4096, N = 20000, F = 768, E = 512;

#define AS1CAST(p) ((__attribute__((address_space(1))) unsigned int*)(uintptr_t)(p))
#define AS3CAST(p) ((__attribute__((address_space(3))) unsigned int*)(uintptr_t)(p))

__device__ __forceinline__ void gload_lds16(const void* g, void* l) {
  // 16B/lane, LDS dest = wave-uniform base + lane*16 (layout guarantees this)
  __builtin_amdgcn_global_load_lds(AS1CAST(g), AS3CAST(l), 16, 0, 0);
}

// ------------------------- slim prep ---------------------------------------
// G fp32->bf16 (tiny), rh = (2r-1)*hw+hb, zero lg/norm2.  Grid covers all.

__global__ void k_prep(const float* __restrict__ G, const float* __restrict__ r,
                       const float* __restrict__ hw, const float* __restrict__ hb,
                       __bf16* __restrict__ Gb, float* __restrict__ rh,
                       float* __restrict__ lg, float* __restrict__ norm2) {
  const int t = blockIdx.x * blockDim.x + threadIdx.x;
  constexpr int nG = E * F / 4;   // 98304 float4 groups
  if (t < nG) {
    float4 v = ((const float4*)G)[t];
    bf16x4 o;
    o[0] = (__bf16)v.x; o[1] = (__bf16)v.y; o[2] = (__bf16)v.z; o[3] = (__bf16)v.w;
    ((bf16x4*)Gb)[t] = o;
  }
  if (t < N) rh[t] = (2.0f * r[t] - 1.0f) * hw[0] + hb[0];
  if (t < B) lg[t] = 0.0f;
  if (t < B + N) norm2[t] = 0.0f;
}

// ------------------------- combined embedding GEMM -------------------------
// row-tiles 0..31 = X, 32..188 = D.  Eb[g,e] = bf16(sum_k A[m,k]G[e,k]+b[e]),
// norm2[g] += sum_e Eb[g,e]^2.  BK=64, XOR-swizzled LDS (conflict-free).
// A-side: reg-staged fp32->bf16 with one-step register prefetch;
// B-side (G): async global_load_lds from pre-converted Gb.

__global__ __launch_bounds__(256, 3)
void k_embed(const float* __restrict__ Xf, const float* __restrict__ Df,
             const __bf16* __restrict__ Gb, const float* __restrict__ bias,
             __bf16* __restrict__ Eb, float* __restrict__ norm2) {
  constexpr int K = F;  // 768
  __shared__ __bf16 As[128 * 64];
  __shared__ __bf16 Bs[128 * 64];
  __shared__ float ssum[128];
  const int tid  = threadIdx.x;
  const int wave = tid >> 6;
  const int lane = tid & 63;
  const int by = blockIdx.y;
  const bool isX = (by < B / 128);
  const float* A = isX ? Xf : Df;
  const int m0 = isX ? by * 128 : (by - B / 128) * 128;
  const int Mr = isX ? B : N;
  const int g0 = by * 128;              // row offset into Eb / norm2
  const int n0 = blockIdx.x * 128;      // e-dim tile
  if (tid < 128) ssum[tid] = 0.0f;

  // staging: thread t -> row=(t>>3)+q*32, global colgrp (t&7)^(row&7).
  // LDS dest element q*2048 + tid*8 == row*64 + (t&7)*8.
  const int srow = tid >> 3;
  const int scg  = (tid & 7) ^ (srow & 7);
  const float*  ga[4];
  const __bf16* gb[4];
  __bf16* la[4];
  __bf16* lb[4];
#pragma unroll
  for (int q = 0; q < 4; ++q) {
    const int row = srow + q * 32;
    int arow = m0 + row; if (arow >= Mr) arow = Mr - 1;
    const int brow = n0 + row;                       // < 512 always
    ga[q] = A  + (size_t)arow * K + scg * 8;
    gb[q] = Gb + (size_t)brow * K + scg * 8;
    la[q] = &As[q * 2048 + tid * 8];
    lb[q] = &Bs[q * 2048 + tid * 8];
  }

  const int mw = (wave & 1) * 64;
  const int nw = (wave >> 1) * 64;
  const int quad = lane >> 4;
  const int l15  = lane & 15;
  f32x4 acc[4][4] = {};

  // preload A step 0 into registers
  float4 av[4][2];
#pragma unroll
  for (int q = 0; q < 4; ++q) {
    av[q][0] = *(const float4*)(ga[q]);
    av[q][1] = *(const float4*)(ga[q] + 4);
  }

#pragma unroll 1
  for (int kb = 0; kb < K; kb += 64) {
    // B: async direct-to-LDS (bf16)
#pragma unroll
    for (int q = 0; q < 4; ++q) gload_lds16(gb[q] + kb, lb[q]);
    // A: cvt current step (av ready - loads issued one step ago)
#pragma unroll
    for (int q = 0; q < 4; ++q) {
      bf16x8 o;
      o[0] = (__bf16)av[q][0].x; o[1] = (__bf16)av[q][0].y;
      o[2] = (__bf16)av[q][0].z; o[3] = (__bf16)av[q][0].w;
      o[4] = (__bf16)av[q][1].x; o[5] = (__bf16)av[q][1].y;
      o[6] = (__bf16)av[q][1].z; o[7] = (__bf16)av[q][1].w;
      *(bf16x8*)la[q] = o;
    }
    // A: prefetch next step into the same (now dead) registers
    if (kb + 64 < K) {
#pragma unroll
      for (int q = 0; q < 4; ++q) {
        av[q][0] = *(const float4*)(ga[q] + kb + 64);
        av[q][1] = *(const float4*)(ga[q] + kb + 68);
      }
    }
    __syncthreads();
#pragma unroll
    for (int h = 0; h < 2; ++h) {
      bf16x8 af[4], bfr[4];
#pragma unroll
      for (int i = 0; i < 4; ++i) {
        const int rr = mw + i * 16 + l15;
        af[i] = *(const bf16x8*)&As[rr * 64 + ((quad + h * 4) ^ (rr & 7)) * 8];
      }
#pragma unroll
      for (int j = 0; j < 4; ++j) {
        const int rr = nw + j * 16 + l15;
        bfr[j] = *(const bf16x8*)&Bs[rr * 64 + ((quad + h * 4) ^ (rr & 7)) * 8];
      }
#pragma unroll
      for (int i = 0; i < 4; ++i)
#pragma unroll
        for (int j = 0; j < 4; ++j)
          acc[i][j] = __builtin_amdgcn_mfma_f32_16x16x32_bf16(af[i], bfr[j], acc[i][j], 0, 0, 0);
    }
    __syncthreads();
  }

  // epilogue: bf16 store + row sum-of-squares.  C/D: col=l15, row=quad*4+reg
#pragma unroll
  for (int i = 0; i < 4; ++i) {
    float part[4] = {0.0f, 0.0f, 0.0f, 0.0f};
#pragma unroll
    for (int j = 0; j < 4; ++j) {
      const int col = n0 + nw + j * 16 + l15;
      const float bv = bias[col];
#pragma unroll
      for (int rr = 0; rr < 4; ++rr) {
        const int row = mw + i * 16 + quad * 4 + rr;   // tile-local
        if (m0 + row < Mr) {
          const __bf16 hv = (__bf16)(acc[i][j][rr] + bv);
          Eb[(size_t)(g0 + row) * E + col] = hv;
          const float vb = (float)hv;
          part[rr] += vb * vb;
        }
      }
    }
#pragma unroll
    for (int rr = 0; rr < 4; ++rr) {
      float v = part[rr];
      v += __shfl_xor(v, 1);
      v += __shfl_xor(v, 2);
      v += __shfl_xor(v, 4);
      v += __shfl_xor(v, 8);
      if (l15 == 0) atomicAdd(&ssum[mw + i * 16 + quad * 4 + rr], v);
    }
  }
  __syncthreads();
  if (tid < 128 && m0 + tid < Mr) atomicAdd(&norm2[g0 + tid], ssum[tid]);
}

// ------------------------- weight precompute -------------------------------
// ix3[row] = (1/max(sqrt(norm2),eps))^3 ; wcol[col] = id^3 * rh[col].

__global__ void k_weights(const float* __restrict__ norm2, const float* __restrict__ rh,
                          float* __restrict__ ix3, float* __restrict__ wcol) {
  const int t = blockIdx.x * blockDim.x + threadIdx.x;
  if (t < B) {
    const float ix = 1.0f / fmaxf(sqrtf(norm2[t]), 1e-12f);
    ix3[t] = ix * ix * ix;
  }
  if (t < N) {
    const float id = 1.0f / fmaxf(sqrtf(norm2[B + t]), 1e-12f);
    wcol[t] = id * id * id * rh[t];
  }
}

// ------------------------- fused Minerva GEMM (32x32x16) -------------------
// acc = Xe@De^T (unnormalized, K=512); epilogue:
//   s^3*rh = acc^3 * ix3[row] * wcol[col]   (all norm math precomputed).
// 32x32x16 MFMA: per K-step 16 MFMA (vs 32 at 16x16x32), same ds_read bytes,
// same 64-AGPR acc -> VGPR budget/occupancy unchanged (16 waves/CU).
// A-frag: lane row=l&31, k-group = 2*slice + (l>>5) (same XOR swizzle).
// C/D (m74/m101): col=lane&31, row=(reg&3)+8*(reg>>2)+4*(lane>>5).

__global__ __launch_bounds__(256, 4)
void k_minerva(const __bf16* __restrict__ Xe, const __bf16* __restrict__ De,
               const float* __restrict__ ix3a, const float* __restrict__ wcol,
               float* __restrict__ logits) {
  constexpr int K  = 512;
  constexpr int MT = B / 128;          // 32
  constexpr int NT = (N + 127) / 128;  // 157
  constexpr int W  = 20;               // panel width (n-tiles)
  __shared__ __bf16 As[128 * 64];
  __shared__ __bf16 Bs[128 * 64];
  __shared__ float lsum[128];
  const int tid  = threadIdx.x;
  const int lane = tid & 63;
  const int wave = tid >> 6;

  // panel decomposition, m-fast within panel
  const int bid   = blockIdx.x;
  const int panel = bid / (W * MT);
  const int bn    = panel * W;
  const int rem   = bid - panel * (W * MT);
  const int mt    = rem % MT;
  const int nt    = bn + rem / MT;
  const int m0 = mt * 128, n0 = nt * 128;
  if (tid < 128) lsum[tid] = 0.0f;

  const int srow = tid >> 3;
  const int scg  = (tid & 7) ^ (srow & 7);
  const __bf16* ga[4];
  const __bf16* gb[4];
  __bf16* la[4];
  __bf16* lb[4];
#pragma unroll
  for (int q = 0; q < 4; ++q) {
    const int row = srow + q * 32;
    const int arow = m0 + row;                       // < 4096 always
    int brow = n0 + row; if (brow >= N) brow = N - 1;
    ga[q] = Xe + (size_t)arow * K + scg * 8;
    gb[q] = De + (size_t)brow * K + scg * 8;
    la[q] = &As[q * 2048 + tid * 8];
    lb[q] = &Bs[q * 2048 + tid * 8];
  }

  const int mw   = (wave & 1) * 64;
  const int nw   = (wave >> 1) * 64;
  const int l31  = lane & 31;
  const int half = lane >> 5;          // 0/1
  f32x16 acc[2][2] = {};               // [A 32-tile][B 32-tile]

  for (int kb = 0; kb < K; kb += 64) {
#pragma unroll
    for (int q = 0; q < 4; ++q) gload_lds16(ga[q] + kb, la[q]);
#pragma unroll
    for (int q = 0; q < 4; ++q) gload_lds16(gb[q] + kb, lb[q]);
    __syncthreads();
#pragma unroll
    for (int s = 0; s < 4; ++s) {      // K=16 slice within the 64-step
      bf16x8 a2[2], b2[2];
#pragma unroll
      for (int i = 0; i < 2; ++i) {
        const int rr = mw + i * 32 + l31;
        a2[i] = *(const bf16x8*)&As[rr * 64 + (((2 * s + half) ^ (rr & 7)) * 8)];
      }
#pragma unroll
      for (int j = 0; j < 2; ++j) {
        const int rr = nw + j * 32 + l31;
        b2[j] = *(const bf16x8*)&Bs[rr * 64 + (((2 * s + half) ^ (rr & 7)) * 8)];
      }
#pragma unroll
      for (int i = 0; i < 2; ++i)
#pragma unroll
        for (int j = 0; j < 2; ++j)
          acc[i][j] = __builtin_amdgcn_mfma_f32_32x32x16_bf16(a2[i], b2[j], acc[i][j], 0, 0, 0);
    }
    __syncthreads();
  }

  // ---- epilogue (weights precomputed; 32x32 C/D layout) ----
  float w2[2];
#pragma unroll
  for (int j = 0; j < 2; ++j) {
    const int col = n0 + nw + j * 32 + l31;
    w2[j] = (col < N) ? wcol[col] : 0.0f;   // kills padded/clamped cols
  }
#pragma unroll
  for (int i = 0; i < 2; ++i) {
#pragma unroll
    for (int r = 0; r < 16; ++r) {
      float v = 0.0f;
#pragma unroll
      for (int j = 0; j < 2; ++j) {
        const float a = acc[i][j][r];
        const float a2v = a * a;
        v = fmaf(a2v * a, w2[j], v);
      }
      v += __shfl_xor(v, 1);
      v += __shfl_xor(v, 2);
      v += __shfl_xor(v, 4);
      v += __shfl_xor(v, 8);
      v += __shfl_xor(v, 16);
      const int lrow = mw + i * 32 + (r & 3) + 8 * (r >> 2) + 4 * half;
      if (l31 == 0) atomicAdd(&lsum[lrow], v * ix3a[m0 + lrow]);
    }
  }
  __syncthreads();
  if (tid < 128) atomicAdd(&logits[m0 + tid], lsum[tid]);
}

// ------------------------- finalize ----------------------------------------

__global__ void k_finalize(const float* __restrict__ logits, float* __restrict__ out, int n) {
  int i = blockIdx.x * blockDim.x + threadIdx.x;
  if (i < n) {
    float L = logits[i];
    out[i] = L;
    out[n + i] = 1.0f / (1.0f + expf(-L));
  }
}

// ------------------------- launcher ----------------------------------------

extern "C" void kernel_launch(void* const* d_in, const int* in_sizes, int n_in,
                              void* d_out, int out_size, void* d_ws, size_t ws_size,
                              hipStream_t stream) {
  const float* X   = (const float*)d_in[0];
  const float* D   = (const float*)d_in[1];
  const float* r   = (const float*)d_in[2];
  const float* g_w = (const float*)d_in[3];
  const float* g_b = (const float*)d_in[4];
  const float* h_w = (const float*)d_in[5];
  const float* h_b = (const float*)d_in[6];
  float* out = (float*)d_out;

  // ws layout (bytes), 256-aligned, total ~25.8 MB
  char* ws = (char*)d_ws;
  __bf16* Gb    = (__bf16*)(ws + 0);             // 512*768*2    = 786,432
  __bf16* Eb    = (__bf16*)(ws + 786432);        // 24096*512*2  = 24,674,304
  float*  rh    = (float*) (ws + 25460736);      // 20000*4      = 80,000
  float*  norm2 = (float*) (ws + 25540736);      // 24096*4      = 96,384
  float*  lg    = (float*) (ws + 25637120);      // 4096*4       = 16,384
  float*  ix3   = (float*) (ws + 25653504);      // 4096*4       = 16,384
  float*  wcol  = (float*) (ws + 25669888);      // 20000*4      = 80,000

  // 1. slim prep: G convert + rh + zero (384*256 = 98304 threads covers all)
  k_prep<<<384, 256, 0, stream>>>(g_w, r, h_w, h_b, Gb, rh, lg, norm2);

  // 2. combined embedding GEMM (A reg-staged from fp32 w/ prefetch)
  k_embed<<<dim3(E / 128, B / 128 + (N + 127) / 128), 256, 0, stream>>>(
      X, D, Gb, g_b, Eb, norm2);

  // 3. normalization weights (tiny)
  k_weights<<<(N + 255) / 256, 256, 0, stream>>>(norm2, rh, ix3, wcol);

  // 4. fused cosine^3-weighted retrieval (precomputed weights in epilogue)
  k_minerva<<<157 * 32, 256, 0, stream>>>(Eb, Eb + (size_t)B * E, ix3, wcol, lg);

  // 5. logits + sigmoid
  k_finalize<<<(B + 255) / 256, 256, 0, stream>>>(lg, out, B);
}

// Round 7
// 267.975 us; speedup vs baseline: 1.0365x; 1.0365x over previous
//
#include <hip/hip_runtime.h>
#include <cstdint>

// ---------------------------------------------------------------------------
// minerva_transform: logits = (l2(Xe) @ l2(De)^T)^3 @ rh ; preds = sigmoid
// R10: k_minerva REVERTED to R8 exact (16x16x32, 101.5us, MfmaUtil 37).
//   R9's 32x32x16 hit a structural 4-way LDS bank conflict (1.03e7): with
//   128B row stride, bank = f(colgroup) only; 32 rows x 1 colgroup per
//   fragment forces 4 lanes/slot. Unfixable by XOR choice; needs padded
//   stride = loses global_load_lds. Abandoned.
// k_embed: 1-phase -> 2-phase double-buffered staging (T3 minimum recipe +
//   T14 issue-early/write-late for the reg-staged A side). Old loop exposed
//   a full HBM round-trip at every K-step's barrier drain (12x/block, only
//   3 blocks/CU to cover). Now stage(t+1) issues before compute(t); the
//   cvt+ds_write lands after compute, into the idle buffer. LDS 32.5->64.5KB
//   (2 blocks/CU) - acceptable, kernel is latency-bound not compute-bound.
// ---------------------------------------------------------------------------

typedef __attribute__((ext_vector_type(4))) float  f32x4;
typedef __attribute__((ext_vector_type(8))) __bf16 bf16x8;
typedef __attribute__((ext_vector_type(4))) __bf16 bf16x4;

constexpr int B = 4096, N = 20000, F = 768, E = 512;

#define AS1CAST(p) ((__attribute__((address_space(1))) unsigned int*)(uintptr_t)(p))
#define AS3CAST(p) ((__attribute__((address_space(3))) unsigned int*)(uintptr_t)(p))

__device__ __forceinline__ void gload_lds16(const void* g, void* l) {
  // 16B/lane, LDS dest = wave-uniform base + lane*16 (layout guarantees this)
  __builtin_amdgcn_global_load_lds(AS1CAST(g), AS3CAST(l), 16, 0, 0);
}

// ------------------------- slim prep ---------------------------------------
// G fp32->bf16 (tiny), rh = (2r-1)*hw+hb, zero lg/norm2.  Grid covers all.

__global__ void k_prep(const float* __restrict__ G, const float* __restrict__ r,
                       const float* __restrict__ hw, const float* __restrict__ hb,
                       __bf16* __restrict__ Gb, float* __restrict__ rh,
                       float* __restrict__ lg, float* __restrict__ norm2) {
  const int t = blockIdx.x * blockDim.x + threadIdx.x;
  constexpr int nG = E * F / 4;   // 98304 float4 groups
  if (t < nG) {
    float4 v = ((const float4*)G)[t];
    bf16x4 o;
    o[0] = (__bf16)v.x; o[1] = (__bf16)v.y; o[2] = (__bf16)v.z; o[3] = (__bf16)v.w;
    ((bf16x4*)Gb)[t] = o;
  }
  if (t < N) rh[t] = (2.0f * r[t] - 1.0f) * hw[0] + hb[0];
  if (t < B) lg[t] = 0.0f;
  if (t < B + N) norm2[t] = 0.0f;
}

// ------------------------- combined embedding GEMM -------------------------
// row-tiles 0..31 = X, 32..188 = D.  Eb[g,e] = bf16(sum_k A[m,k]G[e,k]+b[e]),
// norm2[g] += sum_e Eb[g,e]^2.  BK=64, XOR-swizzled LDS (conflict-free).
// 2-phase double-buffer: stage(t+1) issued before compute(t); A-side
// fp32 loads early, cvt+ds_write late (into idle buffer); one barrier/step.

__global__ __launch_bounds__(256, 2)
void k_embed(const float* __restrict__ Xf, const float* __restrict__ Df,
             const __bf16* __restrict__ Gb, const float* __restrict__ bias,
             __bf16* __restrict__ Eb, float* __restrict__ norm2) {
  constexpr int K  = F;       // 768
  constexpr int NK = K / 64;  // 12 K-steps
  __shared__ __bf16 As[2][128 * 64];
  __shared__ __bf16 Bs[2][128 * 64];
  __shared__ float ssum[128];
  const int tid  = threadIdx.x;
  const int wave = tid >> 6;
  const int lane = tid & 63;
  const int by = blockIdx.y;
  const bool isX = (by < B / 128);
  const float* A = isX ? Xf : Df;
  const int m0 = isX ? by * 128 : (by - B / 128) * 128;
  const int Mr = isX ? B : N;
  const int g0 = by * 128;              // row offset into Eb / norm2
  const int n0 = blockIdx.x * 128;      // e-dim tile
  if (tid < 128) ssum[tid] = 0.0f;

  // staging: thread t -> row=(t>>3)+q*32, global colgrp (t&7)^(row&7).
  // LDS dest element q*2048 + tid*8 == row*64 + (t&7)*8.
  const int srow = tid >> 3;
  const int scg  = (tid & 7) ^ (srow & 7);
  const float*  ga[4];
  const __bf16* gb[4];
  int lo[4];                            // element offset within a buffer
#pragma unroll
  for (int q = 0; q < 4; ++q) {
    const int row = srow + q * 32;
    int arow = m0 + row; if (arow >= Mr) arow = Mr - 1;
    const int brow = n0 + row;                       // < 512 always
    ga[q] = A  + (size_t)arow * K + scg * 8;
    gb[q] = Gb + (size_t)brow * K + scg * 8;
    lo[q] = q * 2048 + tid * 8;
  }

  const int mw = (wave & 1) * 64;
  const int nw = (wave >> 1) * 64;
  const int quad = lane >> 4;
  const int l15  = lane & 15;
  f32x4 acc[4][4] = {};

  // ---- prologue: stage tile 0 into buf 0 ----
#pragma unroll
  for (int q = 0; q < 4; ++q) gload_lds16(gb[q], &Bs[0][lo[q]]);
  {
    float4 a0[4][2];
#pragma unroll
    for (int q = 0; q < 4; ++q) {
      a0[q][0] = *(const float4*)(ga[q]);
      a0[q][1] = *(const float4*)(ga[q] + 4);
    }
#pragma unroll
    for (int q = 0; q < 4; ++q) {
      bf16x8 o;
      o[0] = (__bf16)a0[q][0].x; o[1] = (__bf16)a0[q][0].y;
      o[2] = (__bf16)a0[q][0].z; o[3] = (__bf16)a0[q][0].w;
      o[4] = (__bf16)a0[q][1].x; o[5] = (__bf16)a0[q][1].y;
      o[6] = (__bf16)a0[q][1].z; o[7] = (__bf16)a0[q][1].w;
      *(bf16x8*)&As[0][lo[q]] = o;
    }
  }
  __syncthreads();

#pragma unroll 1
  for (int t = 0; t < NK; ++t) {
    const int cur = t & 1, nxt = cur ^ 1;
    const int kb2 = (t + 1) * 64;
    float4 av[4][2];
    if (t + 1 < NK) {
      // B(t+1): async direct-to-LDS into idle buffer
#pragma unroll
      for (int q = 0; q < 4; ++q) gload_lds16(gb[q] + kb2, &Bs[nxt][lo[q]]);
      // A(t+1): issue fp32 loads early (latency hides under compute below)
#pragma unroll
      for (int q = 0; q < 4; ++q) {
        av[q][0] = *(const float4*)(ga[q] + kb2);
        av[q][1] = *(const float4*)(ga[q] + kb2 + 4);
      }
    }
    // ---- compute from buf[cur] ----
#pragma unroll
    for (int h = 0; h < 2; ++h) {
      bf16x8 af[4], bfr[4];
#pragma unroll
      for (int i = 0; i < 4; ++i) {
        const int rr = mw + i * 16 + l15;
        af[i] = *(const bf16x8*)&As[cur][rr * 64 + ((quad + h * 4) ^ (rr & 7)) * 8];
      }
#pragma unroll
      for (int j = 0; j < 4; ++j) {
        const int rr = nw + j * 16 + l15;
        bfr[j] = *(const bf16x8*)&Bs[cur][rr * 64 + ((quad + h * 4) ^ (rr & 7)) * 8];
      }
#pragma unroll
      for (int i = 0; i < 4; ++i)
#pragma unroll
        for (int j = 0; j < 4; ++j)
          acc[i][j] = __builtin_amdgcn_mfma_f32_16x16x32_bf16(af[i], bfr[j], acc[i][j], 0, 0, 0);
    }
    // ---- write A(t+1) into idle buffer (loads completed under compute) ----
    if (t + 1 < NK) {
#pragma unroll
      for (int q = 0; q < 4; ++q) {
        bf16x8 o;
        o[0] = (__bf16)av[q][0].x; o[1] = (__bf16)av[q][0].y;
        o[2] = (__bf16)av[q][0].z; o[3] = (__bf16)av[q][0].w;
        o[4] = (__bf16)av[q][1].x; o[5] = (__bf16)av[q][1].y;
        o[6] = (__bf16)av[q][1].z; o[7] = (__bf16)av[q][1].w;
        *(bf16x8*)&As[nxt][lo[q]] = o;
      }
    }
    __syncthreads();   // drains gload_lds(B t+1) + ds_write(A t+1)
  }

  // epilogue: bf16 store + row sum-of-squares.  C/D: col=l15, row=quad*4+reg
#pragma unroll
  for (int i = 0; i < 4; ++i) {
    float part[4] = {0.0f, 0.0f, 0.0f, 0.0f};
#pragma unroll
    for (int j = 0; j < 4; ++j) {
      const int col = n0 + nw + j * 16 + l15;
      const float bv = bias[col];
#pragma unroll
      for (int rr = 0; rr < 4; ++rr) {
        const int row = mw + i * 16 + quad * 4 + rr;   // tile-local
        if (m0 + row < Mr) {
          const __bf16 hv = (__bf16)(acc[i][j][rr] + bv);
          Eb[(size_t)(g0 + row) * E + col] = hv;
          const float vb = (float)hv;
          part[rr] += vb * vb;
        }
      }
    }
#pragma unroll
    for (int rr = 0; rr < 4; ++rr) {
      float v = part[rr];
      v += __shfl_xor(v, 1);
      v += __shfl_xor(v, 2);
      v += __shfl_xor(v, 4);
      v += __shfl_xor(v, 8);
      if (l15 == 0) atomicAdd(&ssum[mw + i * 16 + quad * 4 + rr], v);
    }
  }
  __syncthreads();
  if (tid < 128 && m0 + tid < Mr) atomicAdd(&norm2[g0 + tid], ssum[tid]);
}

// ------------------------- weight precompute -------------------------------
// ix3[row] = (1/max(sqrt(norm2),eps))^3 ; wcol[col] = id^3 * rh[col].

__global__ void k_weights(const float* __restrict__ norm2, const float* __restrict__ rh,
                          float* __restrict__ ix3, float* __restrict__ wcol) {
  const int t = blockIdx.x * blockDim.x + threadIdx.x;
  if (t < B) {
    const float ix = 1.0f / fmaxf(sqrtf(norm2[t]), 1e-12f);
    ix3[t] = ix * ix * ix;
  }
  if (t < N) {
    const float id = 1.0f / fmaxf(sqrtf(norm2[B + t]), 1e-12f);
    wcol[t] = id * id * id * rh[t];
  }
}

// ------------------------- fused Minerva GEMM (R8 version) -----------------
// acc = Xe@De^T (unnormalized, K=512); epilogue:
//   s^3*rh = acc^3 * ix3[row] * wcol[col]   (all norm math precomputed).
// m-fast panel ordering for per-XCD L2 fit.  64 arch VGPR + 64 AGPR =
// 128/wave -> 16 waves/CU (the occupancy step).

__global__ __launch_bounds__(256, 4)
void k_minerva(const __bf16* __restrict__ Xe, const __bf16* __restrict__ De,
               const float* __restrict__ ix3a, const float* __restrict__ wcol,
               float* __restrict__ logits) {
  constexpr int K  = 512;
  constexpr int MT = B / 128;          // 32
  constexpr int NT = (N + 127) / 128;  // 157
  constexpr int W  = 20;               // panel width (n-tiles)
  __shared__ __bf16 As[128 * 64];
  __shared__ __bf16 Bs[128 * 64];
  __shared__ float lsum[128];
  const int tid  = threadIdx.x;
  const int lane = tid & 63;
  const int wave = tid >> 6;

  // panel decomposition, m-fast within panel
  const int bid   = blockIdx.x;
  const int panel = bid / (W * MT);
  const int bn    = panel * W;
  const int rem   = bid - panel * (W * MT);
  const int mt    = rem % MT;
  const int nt    = bn + rem / MT;
  const int m0 = mt * 128, n0 = nt * 128;
  if (tid < 128) lsum[tid] = 0.0f;

  const int srow = tid >> 3;
  const int scg  = (tid & 7) ^ (srow & 7);
  const __bf16* ga[4];
  const __bf16* gb[4];
  __bf16* la[4];
  __bf16* lb[4];
#pragma unroll
  for (int q = 0; q < 4; ++q) {
    const int row = srow + q * 32;
    const int arow = m0 + row;                       // < 4096 always
    int brow = n0 + row; if (brow >= N) brow = N - 1;
    ga[q] = Xe + (size_t)arow * K + scg * 8;
    gb[q] = De + (size_t)brow * K + scg * 8;
    la[q] = &As[q * 2048 + tid * 8];
    lb[q] = &Bs[q * 2048 + tid * 8];
  }

  const int mw = (wave & 1) * 64;
  const int nw = (wave >> 1) * 64;
  const int quad = lane >> 4;
  const int l15  = lane & 15;
  f32x4 acc[4][4] = {};

  for (int kb = 0; kb < K; kb += 64) {
#pragma unroll
    for (int q = 0; q < 4; ++q) gload_lds16(ga[q] + kb, la[q]);
#pragma unroll
    for (int q = 0; q < 4; ++q) gload_lds16(gb[q] + kb, lb[q]);
    __syncthreads();
#pragma unroll
    for (int h = 0; h < 2; ++h) {
      bf16x8 af[4], bfr[4];
#pragma unroll
      for (int i = 0; i < 4; ++i) {
        const int rr = mw + i * 16 + l15;
        af[i] = *(const bf16x8*)&As[rr * 64 + ((quad + h * 4) ^ (rr & 7)) * 8];
      }
#pragma unroll
      for (int j = 0; j < 4; ++j) {
        const int rr = nw + j * 16 + l15;
        bfr[j] = *(const bf16x8*)&Bs[rr * 64 + ((quad + h * 4) ^ (rr & 7)) * 8];
      }
#pragma unroll
      for (int i = 0; i < 4; ++i)
#pragma unroll
        for (int j = 0; j < 4; ++j)
          acc[i][j] = __builtin_amdgcn_mfma_f32_16x16x32_bf16(af[i], bfr[j], acc[i][j], 0, 0, 0);
    }
    __syncthreads();
  }

  // ---- epilogue (no transcendentals: all weights precomputed) ----
  float w4[4];
#pragma unroll
  for (int j = 0; j < 4; ++j) {
    const int col = n0 + nw + j * 16 + l15;
    w4[j] = (col < N) ? wcol[col] : 0.0f;   // kills padded/clamped cols
  }
#pragma unroll
  for (int i = 0; i < 4; ++i) {
    float x3[4];
#pragma unroll
    for (int rr = 0; rr < 4; ++rr)
      x3[rr] = ix3a[m0 + mw + i * 16 + quad * 4 + rr];   // broadcast loads
    float part[4] = {0.0f, 0.0f, 0.0f, 0.0f};
#pragma unroll
    for (int j = 0; j < 4; ++j)
#pragma unroll
      for (int rr = 0; rr < 4; ++rr) {
        const float a = acc[i][j][rr];
        const float a2 = a * a;
        part[rr] = fmaf(a2 * a, w4[j], part[rr]);
      }
#pragma unroll
    for (int rr = 0; rr < 4; ++rr) {
      float v = part[rr] * x3[rr];
      v += __shfl_xor(v, 1);
      v += __shfl_xor(v, 2);
      v += __shfl_xor(v, 4);
      v += __shfl_xor(v, 8);
      if (l15 == 0) atomicAdd(&lsum[mw + i * 16 + quad * 4 + rr], v);
    }
  }
  __syncthreads();
  if (tid < 128) atomicAdd(&logits[m0 + tid], lsum[tid]);
}

// ------------------------- finalize ----------------------------------------

__global__ void k_finalize(const float* __restrict__ logits, float* __restrict__ out, int n) {
  int i = blockIdx.x * blockDim.x + threadIdx.x;
  if (i < n) {
    float L = logits[i];
    out[i] = L;
    out[n + i] = 1.0f / (1.0f + expf(-L));
  }
}

// ------------------------- launcher ----------------------------------------

extern "C" void kernel_launch(void* const* d_in, const int* in_sizes, int n_in,
                              void* d_out, int out_size, void* d_ws, size_t ws_size,
                              hipStream_t stream) {
  const float* X   = (const float*)d_in[0];
  const float* D   = (const float*)d_in[1];
  const float* r   = (const float*)d_in[2];
  const float* g_w = (const float*)d_in[3];
  const float* g_b = (const float*)d_in[4];
  const float* h_w = (const float*)d_in[5];
  const float* h_b = (const float*)d_in[6];
  float* out = (float*)d_out;

  // ws layout (bytes), 256-aligned, total ~25.8 MB
  char* ws = (char*)d_ws;
  __bf16* Gb    = (__bf16*)(ws + 0);             // 512*768*2    = 786,432
  __bf16* Eb    = (__bf16*)(ws + 786432);        // 24096*512*2  = 24,674,304
  float*  rh    = (float*) (ws + 25460736);      // 20000*4      = 80,000
  float*  norm2 = (float*) (ws + 25540736);      // 24096*4      = 96,384
  float*  lg    = (float*) (ws + 25637120);      // 4096*4       = 16,384
  float*  ix3   = (float*) (ws + 25653504);      // 4096*4       = 16,384
  float*  wcol  = (float*) (ws + 25669888);      // 20000*4      = 80,000

  // 1. slim prep: G convert + rh + zero (384*256 = 98304 threads covers all)
  k_prep<<<384, 256, 0, stream>>>(g_w, r, h_w, h_b, Gb, rh, lg, norm2);

  // 2. combined embedding GEMM (2-phase pipelined staging)
  k_embed<<<dim3(E / 128, B / 128 + (N + 127) / 128), 256, 0, stream>>>(
      X, D, Gb, g_b, Eb, norm2);

  // 3. normalization weights (tiny)
  k_weights<<<(N + 255) / 256, 256, 0, stream>>>(norm2, rh, ix3, wcol);

  // 4. fused cosine^3-weighted retrieval (precomputed weights in epilogue)
  k_minerva<<<157 * 32, 256, 0, stream>>>(Eb, Eb + (size_t)B * E, ix3, wcol, lg);

  // 5. logits + sigmoid
  k_finalize<<<(B + 255) / 256, 256, 0, stream>>>(lg, out, B);
}

// Round 8
// 251.559 us; speedup vs baseline: 1.1042x; 1.0653x over previous
//
#include <hip/hip_runtime.h>
#include <cstdint>

// ---------------------------------------------------------------------------
// minerva_transform: logits = (l2(Xe) @ l2(De)^T)^3 @ rh ; preds = sigmoid
// R11: assembly of measured-best components.
//  - k_embed: R6-exact (single-phase, NO A-prefetch, (256,3)). Cross-round
//    clock-referenced accounting showed R8's av[4][2] prefetch pushed regs
//    past the 128 occupancy step (16->8 waves/CU -> 2 staging rounds,
//    +25-30us) and R10's 2-phase dbuf cost the same via LDS (3->2 blk/CU).
//  - k_minerva: R8-exact (16x16x32, weights precomputed; 101.5us, MfmaUtil
//    36-37 = the m97-structure ceiling; conflicts 0).
//  - k_prep/k_weights/k_finalize: unchanged.
// ---------------------------------------------------------------------------

typedef __attribute__((ext_vector_type(4))) float  f32x4;
typedef __attribute__((ext_vector_type(8))) __bf16 bf16x8;
typedef __attribute__((ext_vector_type(4))) __bf16 bf16x4;

constexpr int B = 4096, N = 20000, F = 768, E = 512;

#define AS1CAST(p) ((__attribute__((address_space(1))) unsigned int*)(uintptr_t)(p))
#define AS3CAST(p) ((__attribute__((address_space(3))) unsigned int*)(uintptr_t)(p))

__device__ __forceinline__ void gload_lds16(const void* g, void* l) {
  // 16B/lane, LDS dest = wave-uniform base + lane*16 (layout guarantees this)
  __builtin_amdgcn_global_load_lds(AS1CAST(g), AS3CAST(l), 16, 0, 0);
}

// ------------------------- slim prep ---------------------------------------
// G fp32->bf16 (tiny), rh = (2r-1)*hw+hb, zero lg/norm2.  Grid covers all.

__global__ void k_prep(const float* __restrict__ G, const float* __restrict__ r,
                       const float* __restrict__ hw, const float* __restrict__ hb,
                       __bf16* __restrict__ Gb, float* __restrict__ rh,
                       float* __restrict__ lg, float* __restrict__ norm2) {
  const int t = blockIdx.x * blockDim.x + threadIdx.x;
  constexpr int nG = E * F / 4;   // 98304 float4 groups
  if (t < nG) {
    float4 v = ((const float4*)G)[t];
    bf16x4 o;
    o[0] = (__bf16)v.x; o[1] = (__bf16)v.y; o[2] = (__bf16)v.z; o[3] = (__bf16)v.w;
    ((bf16x4*)Gb)[t] = o;
  }
  if (t < N) rh[t] = (2.0f * r[t] - 1.0f) * hw[0] + hb[0];
  if (t < B) lg[t] = 0.0f;
  if (t < B + N) norm2[t] = 0.0f;
}

// ------------------------- combined embedding GEMM -------------------------
// row-tiles 0..31 = X, 32..188 = D.  Eb[g,e] = bf16(sum_k A[m,k]G[e,k]+b[e]),
// norm2[g] += sum_e Eb[g,e]^2.  BK=64, XOR-swizzled LDS (conflict-free).
// A-side: reg-staged fp32->bf16 (load -> cvt -> ds_write, no prefetch: keeps
// arch+AGPR under the 128-reg occupancy step so 3 blocks/CU stay resident);
// B-side (G): async global_load_lds from pre-converted Gb.

__global__ __launch_bounds__(256, 3)
void k_embed(const float* __restrict__ Xf, const float* __restrict__ Df,
             const __bf16* __restrict__ Gb, const float* __restrict__ bias,
             __bf16* __restrict__ Eb, float* __restrict__ norm2) {
  constexpr int K = F;  // 768
  __shared__ __bf16 As[128 * 64];
  __shared__ __bf16 Bs[128 * 64];
  __shared__ float ssum[128];
  const int tid  = threadIdx.x;
  const int wave = tid >> 6;
  const int lane = tid & 63;
  const int by = blockIdx.y;
  const bool isX = (by < B / 128);
  const float* A = isX ? Xf : Df;
  const int m0 = isX ? by * 128 : (by - B / 128) * 128;
  const int Mr = isX ? B : N;
  const int g0 = by * 128;              // row offset into Eb / norm2
  const int n0 = blockIdx.x * 128;      // e-dim tile
  if (tid < 128) ssum[tid] = 0.0f;

  // staging: thread t -> row=(t>>3)+q*32, global colgrp (t&7)^(row&7).
  // LDS dest element q*2048 + tid*8 == row*64 + (t&7)*8.
  const int srow = tid >> 3;
  const int scg  = (tid & 7) ^ (srow & 7);
  const float*  ga[4];
  const __bf16* gb[4];
  __bf16* la[4];
  __bf16* lb[4];
#pragma unroll
  for (int q = 0; q < 4; ++q) {
    const int row = srow + q * 32;
    int arow = m0 + row; if (arow >= Mr) arow = Mr - 1;
    const int brow = n0 + row;                       // < 512 always
    ga[q] = A  + (size_t)arow * K + scg * 8;
    gb[q] = Gb + (size_t)brow * K + scg * 8;
    la[q] = &As[q * 2048 + tid * 8];
    lb[q] = &Bs[q * 2048 + tid * 8];
  }

  const int mw = (wave & 1) * 64;
  const int nw = (wave >> 1) * 64;
  const int quad = lane >> 4;
  const int l15  = lane & 15;
  f32x4 acc[4][4] = {};

  for (int kb = 0; kb < K; kb += 64) {
    // B: async direct-to-LDS (bf16)
#pragma unroll
    for (int q = 0; q < 4; ++q) gload_lds16(gb[q] + kb, lb[q]);
    // A: reg-stage fp32 -> bf16 (issue all loads first for overlap)
    float4 av[4][2];
#pragma unroll
    for (int q = 0; q < 4; ++q) {
      av[q][0] = *(const float4*)(ga[q] + kb);
      av[q][1] = *(const float4*)(ga[q] + kb + 4);
    }
#pragma unroll
    for (int q = 0; q < 4; ++q) {
      bf16x8 o;
      o[0] = (__bf16)av[q][0].x; o[1] = (__bf16)av[q][0].y;
      o[2] = (__bf16)av[q][0].z; o[3] = (__bf16)av[q][0].w;
      o[4] = (__bf16)av[q][1].x; o[5] = (__bf16)av[q][1].y;
      o[6] = (__bf16)av[q][1].z; o[7] = (__bf16)av[q][1].w;
      *(bf16x8*)la[q] = o;
    }
    __syncthreads();
#pragma unroll
    for (int h = 0; h < 2; ++h) {
      bf16x8 af[4], bfr[4];
#pragma unroll
      for (int i = 0; i < 4; ++i) {
        const int rr = mw + i * 16 + l15;
        af[i] = *(const bf16x8*)&As[rr * 64 + ((quad + h * 4) ^ (rr & 7)) * 8];
      }
#pragma unroll
      for (int j = 0; j < 4; ++j) {
        const int rr = nw + j * 16 + l15;
        bfr[j] = *(const bf16x8*)&Bs[rr * 64 + ((quad + h * 4) ^ (rr & 7)) * 8];
      }
#pragma unroll
      for (int i = 0; i < 4; ++i)
#pragma unroll
        for (int j = 0; j < 4; ++j)
          acc[i][j] = __builtin_amdgcn_mfma_f32_16x16x32_bf16(af[i], bfr[j], acc[i][j], 0, 0, 0);
    }
    __syncthreads();
  }

  // epilogue: bf16 store + row sum-of-squares.  C/D: col=l15, row=quad*4+reg
#pragma unroll
  for (int i = 0; i < 4; ++i) {
    float part[4] = {0.0f, 0.0f, 0.0f, 0.0f};
#pragma unroll
    for (int j = 0; j < 4; ++j) {
      const int col = n0 + nw + j * 16 + l15;
      const float bv = bias[col];
#pragma unroll
      for (int rr = 0; rr < 4; ++rr) {
        const int row = mw + i * 16 + quad * 4 + rr;   // tile-local
        if (m0 + row < Mr) {
          const __bf16 hv = (__bf16)(acc[i][j][rr] + bv);
          Eb[(size_t)(g0 + row) * E + col] = hv;
          const float vb = (float)hv;
          part[rr] += vb * vb;
        }
      }
    }
#pragma unroll
    for (int rr = 0; rr < 4; ++rr) {
      float v = part[rr];
      v += __shfl_xor(v, 1);
      v += __shfl_xor(v, 2);
      v += __shfl_xor(v, 4);
      v += __shfl_xor(v, 8);
      if (l15 == 0) atomicAdd(&ssum[mw + i * 16 + quad * 4 + rr], v);
    }
  }
  __syncthreads();
  if (tid < 128 && m0 + tid < Mr) atomicAdd(&norm2[g0 + tid], ssum[tid]);
}

// ------------------------- weight precompute -------------------------------
// ix3[row] = (1/max(sqrt(norm2),eps))^3 ; wcol[col] = id^3 * rh[col].

__global__ void k_weights(const float* __restrict__ norm2, const float* __restrict__ rh,
                          float* __restrict__ ix3, float* __restrict__ wcol) {
  const int t = blockIdx.x * blockDim.x + threadIdx.x;
  if (t < B) {
    const float ix = 1.0f / fmaxf(sqrtf(norm2[t]), 1e-12f);
    ix3[t] = ix * ix * ix;
  }
  if (t < N) {
    const float id = 1.0f / fmaxf(sqrtf(norm2[B + t]), 1e-12f);
    wcol[t] = id * id * id * rh[t];
  }
}

// ------------------------- fused Minerva GEMM (R8 version) -----------------
// acc = Xe@De^T (unnormalized, K=512); epilogue:
//   s^3*rh = acc^3 * ix3[row] * wcol[col]   (all norm math precomputed).
// m-fast panel ordering for per-XCD L2 fit.  64 arch VGPR + 64 AGPR =
// 128/wave -> 16 waves/CU (the occupancy step).

__global__ __launch_bounds__(256, 4)
void k_minerva(const __bf16* __restrict__ Xe, const __bf16* __restrict__ De,
               const float* __restrict__ ix3a, const float* __restrict__ wcol,
               float* __restrict__ logits) {
  constexpr int K  = 512;
  constexpr int MT = B / 128;          // 32
  constexpr int NT = (N + 127) / 128;  // 157
  constexpr int W  = 20;               // panel width (n-tiles)
  __shared__ __bf16 As[128 * 64];
  __shared__ __bf16 Bs[128 * 64];
  __shared__ float lsum[128];
  const int tid  = threadIdx.x;
  const int lane = tid & 63;
  const int wave = tid >> 6;

  // panel decomposition, m-fast within panel
  const int bid   = blockIdx.x;
  const int panel = bid / (W * MT);
  const int bn    = panel * W;
  const int rem   = bid - panel * (W * MT);
  const int mt    = rem % MT;
  const int nt    = bn + rem / MT;
  const int m0 = mt * 128, n0 = nt * 128;
  if (tid < 128) lsum[tid] = 0.0f;

  const int srow = tid >> 3;
  const int scg  = (tid & 7) ^ (srow & 7);
  const __bf16* ga[4];
  const __bf16* gb[4];
  __bf16* la[4];
  __bf16* lb[4];
#pragma unroll
  for (int q = 0; q < 4; ++q) {
    const int row = srow + q * 32;
    const int arow = m0 + row;                       // < 4096 always
    int brow = n0 + row; if (brow >= N) brow = N - 1;
    ga[q] = Xe + (size_t)arow * K + scg * 8;
    gb[q] = De + (size_t)brow * K + scg * 8;
    la[q] = &As[q * 2048 + tid * 8];
    lb[q] = &Bs[q * 2048 + tid * 8];
  }

  const int mw = (wave & 1) * 64;
  const int nw = (wave >> 1) * 64;
  const int quad = lane >> 4;
  const int l15  = lane & 15;
  f32x4 acc[4][4] = {};

  for (int kb = 0; kb < K; kb += 64) {
#pragma unroll
    for (int q = 0; q < 4; ++q) gload_lds16(ga[q] + kb, la[q]);
#pragma unroll
    for (int q = 0; q < 4; ++q) gload_lds16(gb[q] + kb, lb[q]);
    __syncthreads();
#pragma unroll
    for (int h = 0; h < 2; ++h) {
      bf16x8 af[4], bfr[4];
#pragma unroll
      for (int i = 0; i < 4; ++i) {
        const int rr = mw + i * 16 + l15;
        af[i] = *(const bf16x8*)&As[rr * 64 + ((quad + h * 4) ^ (rr & 7)) * 8];
      }
#pragma unroll
      for (int j = 0; j < 4; ++j) {
        const int rr = nw + j * 16 + l15;
        bfr[j] = *(const bf16x8*)&Bs[rr * 64 + ((quad + h * 4) ^ (rr & 7)) * 8];
      }
#pragma unroll
      for (int i = 0; i < 4; ++i)
#pragma unroll
        for (int j = 0; j < 4; ++j)
          acc[i][j] = __builtin_amdgcn_mfma_f32_16x16x32_bf16(af[i], bfr[j], acc[i][j], 0, 0, 0);
    }
    __syncthreads();
  }

  // ---- epilogue (no transcendentals: all weights precomputed) ----
  float w4[4];
#pragma unroll
  for (int j = 0; j < 4; ++j) {
    const int col = n0 + nw + j * 16 + l15;
    w4[j] = (col < N) ? wcol[col] : 0.0f;   // kills padded/clamped cols
  }
#pragma unroll
  for (int i = 0; i < 4; ++i) {
    float x3[4];
#pragma unroll
    for (int rr = 0; rr < 4; ++rr)
      x3[rr] = ix3a[m0 + mw + i * 16 + quad * 4 + rr];   // broadcast loads
    float part[4] = {0.0f, 0.0f, 0.0f, 0.0f};
#pragma unroll
    for (int j = 0; j < 4; ++j)
#pragma unroll
      for (int rr = 0; rr < 4; ++rr) {
        const float a = acc[i][j][rr];
        const float a2 = a * a;
        part[rr] = fmaf(a2 * a, w4[j], part[rr]);
      }
#pragma unroll
    for (int rr = 0; rr < 4; ++rr) {
      float v = part[rr] * x3[rr];
      v += __shfl_xor(v, 1);
      v += __shfl_xor(v, 2);
      v += __shfl_xor(v, 4);
      v += __shfl_xor(v, 8);
      if (l15 == 0) atomicAdd(&lsum[mw + i * 16 + quad * 4 + rr], v);
    }
  }
  __syncthreads();
  if (tid < 128) atomicAdd(&logits[m0 + tid], lsum[tid]);
}

// ------------------------- finalize ----------------------------------------

__global__ void k_finalize(const float* __restrict__ logits, float* __restrict__ out, int n) {
  int i = blockIdx.x * blockDim.x + threadIdx.x;
  if (i < n) {
    float L = logits[i];
    out[i] = L;
    out[n + i] = 1.0f / (1.0f + expf(-L));
  }
}

// ------------------------- launcher ----------------------------------------

extern "C" void kernel_launch(void* const* d_in, const int* in_sizes, int n_in,
                              void* d_out, int out_size, void* d_ws, size_t ws_size,
                              hipStream_t stream) {
  const float* X   = (const float*)d_in[0];
  const float* D   = (const float*)d_in[1];
  const float* r   = (const float*)d_in[2];
  const float* g_w = (const float*)d_in[3];
  const float* g_b = (const float*)d_in[4];
  const float* h_w = (const float*)d_in[5];
  const float* h_b = (const float*)d_in[6];
  float* out = (float*)d_out;

  // ws layout (bytes), 256-aligned, total ~25.8 MB
  char* ws = (char*)d_ws;
  __bf16* Gb    = (__bf16*)(ws + 0);             // 512*768*2    = 786,432
  __bf16* Eb    = (__bf16*)(ws + 786432);        // 24096*512*2  = 24,674,304
  float*  rh    = (float*) (ws + 25460736);      // 20000*4      = 80,000
  float*  norm2 = (float*) (ws + 25540736);      // 24096*4      = 96,384
  float*  lg    = (float*) (ws + 25637120);      // 4096*4       = 16,384
  float*  ix3   = (float*) (ws + 25653504);      // 4096*4       = 16,384
  float*  wcol  = (float*) (ws + 25669888);      // 20000*4      = 80,000

  // 1. slim prep: G convert + rh + zero (384*256 = 98304 threads covers all)
  k_prep<<<384, 256, 0, stream>>>(g_w, r, h_w, h_b, Gb, rh, lg, norm2);

  // 2. combined embedding GEMM (A reg-staged from fp32, single-phase)
  k_embed<<<dim3(E / 128, B / 128 + (N + 127) / 128), 256, 0, stream>>>(
      X, D, Gb, g_b, Eb, norm2);

  // 3. normalization weights (tiny)
  k_weights<<<(N + 255) / 256, 256, 0, stream>>>(norm2, rh, ix3, wcol);

  // 4. fused cosine^3-weighted retrieval (precomputed weights in epilogue)
  k_minerva<<<157 * 32, 256, 0, stream>>>(Eb, Eb + (size_t)B * E, ix3, wcol, lg);

  // 5. logits + sigmoid
  k_finalize<<<(B + 255) / 256, 256, 0, stream>>>(lg, out, B);
}